// Round 2
// baseline (511.900 us; speedup 1.0000x reference)
//
#include <hip/hip_runtime.h>
#include <hip/hip_bf16.h>

// AUGRU: T=200, B=4096, D=64, H=64.
// One block = 16 batch rows, 4 waves (256 thr). Wave w owns gate tiles
// {w, w+4, w+8} = (r,z,n) gates for hidden cols [16w, 16w+16).
// Weights live in registers as MFMA B-fragments; h double-buffers in LDS
// (bf16, XOR-swizzled). One barrier per timestep. x[t+1] prefetched.

#define T_STEPS 200
#define BATCH   4096

typedef __attribute__((ext_vector_type(8))) __bf16 bf16x8;
typedef __attribute__((ext_vector_type(4))) float  f32x4;

__global__ __launch_bounds__(256) void augru_kernel(
    const float* __restrict__ x,        // (T,B,64)
    const float* __restrict__ wts,      // (T,B,1)
    const int*   __restrict__ lengths,  // (B)
    const float* __restrict__ W_ih,     // (192,64)
    const float* __restrict__ W_hh,     // (192,64)
    const float* __restrict__ b_ih,     // (192)
    const float* __restrict__ b_hh,     // (192)
    float* __restrict__ out)            // (T,B,64)
{
    const int tid   = threadIdx.x;
    const int wave  = tid >> 6;       // 0..3
    const int lane  = tid & 63;
    const int l15   = lane & 15;
    const int lhi   = lane >> 4;      // 0..3
    const int rbase = blockIdx.x * 16;
    const int j     = wave * 16 + l15;   // hidden col this lane owns in C-layout

    __shared__ __bf16 hbuf[2][16 * 64];  // [parity][row*64 + col], XOR-swizzled
    __shared__ int smax;

    if (tid == 0) smax = 1;
    for (int i = tid; i < 1024; i += 256) hbuf[0][i] = (__bf16)0.0f;

    // ---- weight B-fragments in registers ----
    // B[k][n] = W[gate_row = tile*16 + l15][k], lane holds 8 consecutive k at
    // k = c*32 + lhi*8 (mfma_16x16x32 B layout).
    bf16x8 wih[3][2], whh[3][2];
#pragma unroll
    for (int g = 0; g < 3; ++g) {
        const int grow = (g * 4 + wave) * 16 + l15;   // 0..191
#pragma unroll
        for (int c = 0; c < 2; ++c) {
            const float* pih = W_ih + grow * 64 + c * 32 + lhi * 8;
            const float* phh = W_hh + grow * 64 + c * 32 + lhi * 8;
#pragma unroll
            for (int i = 0; i < 8; ++i) {
                wih[g][c][i] = (__bf16)pih[i];
                whh[g][c][i] = (__bf16)phh[i];
            }
        }
    }

    const float bir = b_ih[j],       bhr = b_hh[j];
    const float biz = b_ih[64 + j],  bhz = b_hh[64 + j];
    const float bin = b_ih[128 + j], bhn = b_hh[128 + j];

    int   row[4], len[4];
    float hprev[4];
#pragma unroll
    for (int i = 0; i < 4; ++i) {
        row[i]   = rbase + lhi * 4 + i;   // C-layout: row = (lane>>4)*4 + reg
        len[i]   = lengths[row[i]];
        hprev[i] = 0.0f;
    }
    {   // block max length (robust even if not sorted)
        int ml = max(max(len[0], len[1]), max(len[2], len[3]));
        __syncthreads();               // smax init + hbuf[0] zero visible
        atomicMax(&smax, ml);
    }

    // ---- prefetch x[0], w[0] ----
    f32x4 xn0, xn1, xn2, xn3; float wtn[4];
    {
        const float* p = x + (size_t)(rbase + l15) * 64 + lhi * 8;
        xn0 = *(const f32x4*)(p);        xn1 = *(const f32x4*)(p + 4);
        xn2 = *(const f32x4*)(p + 32);   xn3 = *(const f32x4*)(p + 32 + 4);
#pragma unroll
        for (int i = 0; i < 4; ++i) wtn[i] = wts[row[i]];
    }

    __syncthreads();
    const int maxlen = smax;

    for (int t = 0; t < maxlen; ++t) {
        f32x4 xc0 = xn0, xc1 = xn1, xc2 = xn2, xc3 = xn3;
        float wt[4];
#pragma unroll
        for (int i = 0; i < 4; ++i) wt[i] = wtn[i];

        // prefetch next step (clamped)
        const int tn = (t + 1 < T_STEPS) ? t + 1 : t;
        {
            const float* p = x + (size_t)tn * (BATCH * 64)
                               + (size_t)(rbase + l15) * 64 + lhi * 8;
            xn0 = *(const f32x4*)(p);        xn1 = *(const f32x4*)(p + 4);
            xn2 = *(const f32x4*)(p + 32);   xn3 = *(const f32x4*)(p + 32 + 4);
#pragma unroll
            for (int i = 0; i < 4; ++i) wtn[i] = wts[(size_t)tn * BATCH + row[i]];
        }

        // x -> A fragments (row = l15, k = c*32 + lhi*8 + i)
        bf16x8 xf0, xf1;
#pragma unroll
        for (int i = 0; i < 4; ++i) {
            xf0[i]     = (__bf16)xc0[i];
            xf0[i + 4] = (__bf16)xc1[i];
            xf1[i]     = (__bf16)xc2[i];
            xf1[i + 4] = (__bf16)xc3[i];
        }

        // gi = x @ W_ih^T  (3 gate tiles x K=64)
        f32x4 gi0 = {0,0,0,0}, gi1 = {0,0,0,0}, gi2 = {0,0,0,0};
        gi0 = __builtin_amdgcn_mfma_f32_16x16x32_bf16(xf0, wih[0][0], gi0, 0,0,0);
        gi1 = __builtin_amdgcn_mfma_f32_16x16x32_bf16(xf0, wih[1][0], gi1, 0,0,0);
        gi2 = __builtin_amdgcn_mfma_f32_16x16x32_bf16(xf0, wih[2][0], gi2, 0,0,0);
        gi0 = __builtin_amdgcn_mfma_f32_16x16x32_bf16(xf1, wih[0][1], gi0, 0,0,0);
        gi1 = __builtin_amdgcn_mfma_f32_16x16x32_bf16(xf1, wih[1][1], gi1, 0,0,0);
        gi2 = __builtin_amdgcn_mfma_f32_16x16x32_bf16(xf1, wih[2][1], gi2, 0,0,0);

        // h A-fragments from LDS (swizzled)
        const int pr = t & 1;
        bf16x8 hf0, hf1;
        {
            const int base = l15 * 64;
            const int sw   = (l15 & 7) << 3;
            hf0 = *(const bf16x8*)&hbuf[pr][base + ((lhi * 8)      ^ sw)];
            hf1 = *(const bf16x8*)&hbuf[pr][base + ((32 + lhi * 8) ^ sw)];
        }

        f32x4 gh0 = {0,0,0,0}, gh1 = {0,0,0,0}, gh2 = {0,0,0,0};
        gh0 = __builtin_amdgcn_mfma_f32_16x16x32_bf16(hf0, whh[0][0], gh0, 0,0,0);
        gh1 = __builtin_amdgcn_mfma_f32_16x16x32_bf16(hf0, whh[1][0], gh1, 0,0,0);
        gh2 = __builtin_amdgcn_mfma_f32_16x16x32_bf16(hf0, whh[2][0], gh2, 0,0,0);
        gh0 = __builtin_amdgcn_mfma_f32_16x16x32_bf16(hf1, whh[0][1], gh0, 0,0,0);
        gh1 = __builtin_amdgcn_mfma_f32_16x16x32_bf16(hf1, whh[1][1], gh1, 0,0,0);
        gh2 = __builtin_amdgcn_mfma_f32_16x16x32_bf16(hf1, whh[2][1], gh2, 0,0,0);

        // elementwise gates + state update
        const int pw = (t + 1) & 1;
        float* outp = out + (size_t)t * (BATCH * 64);
#pragma unroll
        for (int i = 0; i < 4; ++i) {
            const float sr = (gi0[i] + bir) + (gh0[i] + bhr);
            const float sz = (gi1[i] + biz) + (gh1[i] + bhz);
            const float in_ = gi2[i] + bin;
            const float hn  = gh2[i] + bhn;
            const float r = 1.0f / (1.0f + __expf(-sr));
            const float z = 1.0f / (1.0f + __expf(-sz));
            const float v = in_ + r * hn;
            const float n = 1.0f - 2.0f / (1.0f + __expf(2.0f * v));   // tanh(v)
            const float u  = wt[i] * z;
            const float hy = (1.0f - u) * hprev[i] + u * n;
            const bool act = (t < len[i]);
            const float hnew = act ? hy : hprev[i];
            hprev[i] = hnew;
            __builtin_nontemporal_store(act ? hy : 0.0f,
                                        outp + (size_t)row[i] * 64 + j);
            const int lrow = lhi * 4 + i;
            hbuf[pw][(lrow * 64 + j) ^ ((lrow & 7) << 3)] = (__bf16)hnew;
        }
        __syncthreads();
    }

    // tail: all rows in this block are done -> stream zeros (coalesced)
    {
        const f32x4 z4 = {0, 0, 0, 0};
        for (int t = maxlen; t < T_STEPS; ++t) {
            float* p = out + (size_t)t * (BATCH * 64) + (size_t)rbase * 64 + tid * 4;
            __builtin_nontemporal_store(z4, (f32x4*)p);
        }
    }
}

extern "C" void kernel_launch(void* const* d_in, const int* in_sizes, int n_in,
                              void* d_out, int out_size, void* d_ws, size_t ws_size,
                              hipStream_t stream) {
    const float* x    = (const float*)d_in[0];
    const float* wts  = (const float*)d_in[1];
    const int*   len  = (const int*)  d_in[2];
    const float* W_ih = (const float*)d_in[3];
    const float* W_hh = (const float*)d_in[4];
    const float* b_ih = (const float*)d_in[5];
    const float* b_hh = (const float*)d_in[6];
    float* outp = (float*)d_out;

    dim3 grid(BATCH / 16), block(256);
    augru_kernel<<<grid, block, 0, stream>>>(x, wts, len, W_ih, W_hh, b_ih, b_hh, outp);
}

// Round 5
// 442.399 us; speedup vs baseline: 1.1571x; 1.1571x over previous
//
#include <hip/hip_runtime.h>
#include <hip/hip_bf16.h>

// AUGRU: T=200, B=4096, D=64, H=64.
// One block = 16 batch rows, 4 waves. Wave w owns gate tiles {w,w+4,w+8}
// = (r,z,n) for hidden cols [16w,16w+16). Weights in registers as MFMA
// B-fragments; h double-buffered in LDS (bf16, XOR-swizzled).
// KEY (R2 fix): raw s_barrier + lgkmcnt(0) only — __syncthreads()'s
// vmcnt(0) drain was serializing the x prefetch + out stores into every
// step (3100 cy/step). x/wts prefetched 2 steps ahead, stays in flight
// across barriers.

#define T_STEPS 200
#define BATCH   4096

typedef __attribute__((ext_vector_type(8))) __bf16 bf16x8;
typedef __attribute__((ext_vector_type(4))) float  f32x4;

#define MFMA16(a, b, c) __builtin_amdgcn_mfma_f32_16x16x32_bf16((a), (b), (c), 0, 0, 0)

__global__ __launch_bounds__(256) void augru_kernel(
    const float* __restrict__ x,        // (T,B,64)
    const float* __restrict__ wts,      // (T,B,1)
    const int*   __restrict__ lengths,  // (B)
    const float* __restrict__ W_ih,     // (192,64)
    const float* __restrict__ W_hh,     // (192,64)
    const float* __restrict__ b_ih,     // (192)
    const float* __restrict__ b_hh,     // (192)
    float* __restrict__ out)            // (T,B,64)
{
    const int tid   = threadIdx.x;
    const int wave  = tid >> 6;
    const int lane  = tid & 63;
    const int l15   = lane & 15;
    const int lhi   = lane >> 4;
    const int rbase = blockIdx.x * 16;
    const int j     = wave * 16 + l15;

    __shared__ __bf16 hbuf[2][16 * 64];
    __shared__ int smax;

    if (tid == 0) smax = 1;
    for (int i = tid; i < 1024; i += 256) hbuf[0][i] = (__bf16)0.0f;

    // weight B-fragments: B[k][n] = W[tile*16+l15][k], 8 k's at c*32+lhi*8
    bf16x8 wih[3][2], whh[3][2];
#pragma unroll
    for (int g = 0; g < 3; ++g) {
        const int grow = (g * 4 + wave) * 16 + l15;
#pragma unroll
        for (int c = 0; c < 2; ++c) {
            const float* pih = W_ih + grow * 64 + c * 32 + lhi * 8;
            const float* phh = W_hh + grow * 64 + c * 32 + lhi * 8;
#pragma unroll
            for (int i = 0; i < 8; ++i) {
                wih[g][c][i] = (__bf16)pih[i];
                whh[g][c][i] = (__bf16)phh[i];
            }
        }
    }

    const float brsum = b_ih[j] + b_hh[j];
    const float bzsum = b_ih[64 + j] + b_hh[64 + j];
    const float bin = b_ih[128 + j], bhn = b_hh[128 + j];

    int   row[4], len[4];
    float hprev[4];
#pragma unroll
    for (int i = 0; i < 4; ++i) {
        row[i]   = rbase + lhi * 4 + i;
        len[i]   = lengths[row[i]];
        hprev[i] = 0.0f;
    }
    {
        int ml = max(max(len[0], len[1]), max(len[2], len[3]));
        __syncthreads();               // smax init + hbuf[0] zeros visible
        atomicMax(&smax, ml);
    }

    auto load_x = [&](int t, f32x4& a0, f32x4& a1, f32x4& a2, f32x4& a3) {
        const float* p = x + (size_t)t * (BATCH * 64)
                           + (size_t)(rbase + l15) * 64 + lhi * 8;
        a0 = *(const f32x4*)(p);        a1 = *(const f32x4*)(p + 4);
        a2 = *(const f32x4*)(p + 32);   a3 = *(const f32x4*)(p + 32 + 4);
    };
    auto load_w = [&](int t, float (&w4)[4]) {
#pragma unroll
        for (int i = 0; i < 4; ++i) w4[i] = wts[(size_t)t * BATCH + row[i]];
    };

    // 2-deep prefetch: A = even steps, B = odd steps
    f32x4 A0, A1, A2, A3, B0, B1, B2, B3;
    float wtA[4], wtB[4];
    load_x(0, A0, A1, A2, A3); load_w(0, wtA);
    load_x(1, B0, B1, B2, B3); load_w(1, wtB);

    __syncthreads();
    const int maxlen = smax;

    auto do_step = [&](int t, f32x4& a0, f32x4& a1, f32x4& a2, f32x4& a3,
                       float (&wtc)[4]) {
        // h fragments from LDS (issue early; written before last barrier)
        const int pr = t & 1;
        bf16x8 hf0, hf1;
        {
            const int base = l15 * 64;
            const int sw   = (l15 & 7) << 3;
            hf0 = *(const bf16x8*)&hbuf[pr][base + ((lhi * 8)      ^ sw)];
            hf1 = *(const bf16x8*)&hbuf[pr][base + ((32 + lhi * 8) ^ sw)];
        }
        // consume x registers
        bf16x8 xf0, xf1;
#pragma unroll
        for (int i = 0; i < 4; ++i) {
            xf0[i]     = (__bf16)a0[i];
            xf0[i + 4] = (__bf16)a1[i];
            xf1[i]     = (__bf16)a2[i];
            xf1[i + 4] = (__bf16)a3[i];
        }
        float wt[4];
#pragma unroll
        for (int i = 0; i < 4; ++i) wt[i] = wtc[i];

        // prefetch t+2 into the same register set (WAR keeps ordering);
        // stays in flight across the raw barriers below.
        const int tn = (t + 2 < T_STEPS) ? t + 2 : T_STEPS - 1;
        load_x(tn, a0, a1, a2, a3);
        load_w(tn, wtc);

        // fused accumulators: r,z get gi+gh summed in-MFMA; n stays split
        f32x4 accR = {0,0,0,0}, accZ = {0,0,0,0};
        f32x4 giN  = {0,0,0,0}, ghN  = {0,0,0,0};
        accR = MFMA16(xf0, wih[0][0], accR);
        accR = MFMA16(xf1, wih[0][1], accR);
        accZ = MFMA16(xf0, wih[1][0], accZ);
        accZ = MFMA16(xf1, wih[1][1], accZ);
        giN  = MFMA16(xf0, wih[2][0], giN);
        giN  = MFMA16(xf1, wih[2][1], giN);
        accR = MFMA16(hf0, whh[0][0], accR);
        accR = MFMA16(hf1, whh[0][1], accR);
        accZ = MFMA16(hf0, whh[1][0], accZ);
        accZ = MFMA16(hf1, whh[1][1], accZ);
        ghN  = MFMA16(hf0, whh[2][0], ghN);
        ghN  = MFMA16(hf1, whh[2][1], ghN);

        const int pw = (t + 1) & 1;
        float* outp = out + (size_t)t * (BATCH * 64);
#pragma unroll
        for (int i = 0; i < 4; ++i) {
            const float r = __builtin_amdgcn_rcpf(1.0f + __expf(-(accR[i] + brsum)));
            const float z = __builtin_amdgcn_rcpf(1.0f + __expf(-(accZ[i] + bzsum)));
            const float v = (giN[i] + bin) + r * (ghN[i] + bhn);
            const float n = 1.0f - 2.0f * __builtin_amdgcn_rcpf(1.0f + __expf(2.0f * v));
            const float u  = wt[i] * z;
            const float hy = hprev[i] + u * (n - hprev[i]);
            const bool act = (t < len[i]);
            const float hnew = act ? hy : hprev[i];
            hprev[i] = hnew;
            __builtin_nontemporal_store(act ? hy : 0.0f,
                                        outp + (size_t)row[i] * 64 + j);
            const int lrow = lhi * 4 + i;
            hbuf[pw][(lrow * 64 + j) ^ ((lrow & 7) << 3)] = (__bf16)hnew;
        }

        // raw barrier: drain LDS (writes visible + our reads done) but keep
        // global loads/stores in flight. sched_barrier pins ordering (#18).
        asm volatile("s_waitcnt lgkmcnt(0)" ::: "memory");
        __builtin_amdgcn_sched_barrier(0);
        __builtin_amdgcn_s_barrier();
        __builtin_amdgcn_sched_barrier(0);
    };

    for (int t = 0; t < maxlen; t += 2) {
        do_step(t, A0, A1, A2, A3, wtA);
        if (t + 1 < maxlen)                   // maxlen is block-uniform
            do_step(t + 1, B0, B1, B2, B3, wtB);
    }

    // tail: all rows in this block done -> stream zeros (coalesced)
    {
        const f32x4 z4 = {0, 0, 0, 0};
        for (int t = maxlen; t < T_STEPS; ++t) {
            float* p = out + (size_t)t * (BATCH * 64) + (size_t)rbase * 64 + tid * 4;
            __builtin_nontemporal_store(z4, (f32x4*)p);
        }
    }
}

extern "C" void kernel_launch(void* const* d_in, const int* in_sizes, int n_in,
                              void* d_out, int out_size, void* d_ws, size_t ws_size,
                              hipStream_t stream) {
    const float* x    = (const float*)d_in[0];
    const float* wts  = (const float*)d_in[1];
    const int*   len  = (const int*)  d_in[2];
    const float* W_ih = (const float*)d_in[3];
    const float* W_hh = (const float*)d_in[4];
    const float* b_ih = (const float*)d_in[5];
    const float* b_hh = (const float*)d_in[6];
    float* outp = (float*)d_out;

    dim3 grid(BATCH / 16), block(256);
    augru_kernel<<<grid, block, 0, stream>>>(x, wts, len, W_ih, W_hh, b_ih, b_hh, outp);
}